// Round 7
// baseline (55855.377 us; speedup 1.0000x reference)
//
#include <hip/hip_runtime.h>
#include <cstddef>
#include <cstdint>

typedef float v2f __attribute__((ext_vector_type(2)));

// ---------------------------------------------------------------------------
// fc1: y[r] = W[r,:] . x + b[r]    (wave per row, 4 rows/block)
// ---------------------------------------------------------------------------
__global__ void fc1_k(const float* __restrict__ W, const float* __restrict__ x,
                      const float* __restrict__ b, float* __restrict__ y,
                      int rows, int cols) {
  int wave = threadIdx.x >> 6, lane = threadIdx.x & 63;
  int r = blockIdx.x * 4 + wave;
  if (r >= rows) return;
  const float* wp = W + (size_t)r * cols;
  float s = 0.f;
  for (int j = lane; j < cols; j += 64) s = fmaf(wp[j], x[j], s);
  for (int o = 32; o; o >>= 1) s += __shfl_down(s, o);
  if (lane == 0) y[r] = s + b[r];
}

// ---------------------------------------------------------------------------
// conv: SAME-pad (1,2) k=4 s=1 cross-correlation, optionally fused with
// nearest-neighbor x2 upsample of the input (UP=1).
// ---------------------------------------------------------------------------
template <int UP>
__global__ void conv_k(const float* __restrict__ in, const float* __restrict__ wt,
                       float* __restrict__ out, int Cin, int Cout, int OH, int OW,
                       int Hin, int Win) {
  int idx = blockIdx.x * blockDim.x + threadIdx.x;
  int total = Cout * OH * OW;
  if (idx >= total) return;
  int ox = idx % OW;
  int tt = idx / OW;
  int oy = tt % OH;
  int co = tt / OH;
  const float* wco = wt + (size_t)co * Cin * 16;
  float acc = 0.f;
  for (int ci = 0; ci < Cin; ++ci) {
    const float* ip = in + (size_t)ci * Hin * Win;
    const float* wp = wco + ci * 16;
#pragma unroll
    for (int ky = 0; ky < 4; ++ky) {
      int iy = oy - 1 + ky;
      if ((unsigned)iy >= (unsigned)OH) continue;  // zero pad
      int sy = UP ? (iy >> 1) : iy;
      const float* iprow = ip + sy * Win;
#pragma unroll
      for (int kx = 0; kx < 4; ++kx) {
        int ix = ox - 1 + kx;
        if ((unsigned)ix >= (unsigned)OW) continue;  // zero pad
        int sx = UP ? (ix >> 1) : ix;
        acc = fmaf(iprow[sx], wp[ky * 4 + kx], acc);
      }
    }
  }
  out[idx] = acc;
}

// ---------------------------------------------------------------------------
// BatchNorm training-mode stats (N=1), double accumulation.
// ---------------------------------------------------------------------------
__global__ void stats_k(const float* __restrict__ x, float* __restrict__ mean,
                        float* __restrict__ rstd, int HW) {
  int c = blockIdx.x;
  const float* p = x + (size_t)c * HW;
  double s = 0.0, s2 = 0.0;
  for (int i = threadIdx.x; i < HW; i += blockDim.x) {
    float v = p[i];
    s += v;
    s2 += (double)v * (double)v;
  }
  for (int o = 32; o; o >>= 1) {
    s += __shfl_down(s, o);
    s2 += __shfl_down(s2, o);
  }
  __shared__ double sh[2][4];
  int wv = threadIdx.x >> 6, ln = threadIdx.x & 63;
  if (ln == 0) { sh[0][wv] = s; sh[1][wv] = s2; }
  __syncthreads();
  if (threadIdx.x == 0) {
    double S = 0, S2 = 0;
    int nw = blockDim.x >> 6;
    for (int w = 0; w < nw; ++w) { S += sh[0][w]; S2 += sh[1][w]; }
    double m = S / HW;
    double v = S2 / HW - m * m;
    if (v < 0) v = 0;
    mean[c] = (float)m;
    rstd[c] = rsqrtf((float)v + 1e-5f);
  }
}

__global__ void bnrelu_k(float* __restrict__ x, const float* __restrict__ mean,
                         const float* __restrict__ rstd, const float* __restrict__ g,
                         const float* __restrict__ be, int HW, int total) {
  int idx = blockIdx.x * blockDim.x + threadIdx.x;
  if (idx >= total) return;
  int c = idx / HW;
  float v = (x[idx] - mean[c]) * rstd[c] * g[c] + be[c];
  x[idx] = v > 0.f ? v : 0.f;
}

__global__ void tanh_k(float* __restrict__ x, int n) {
  int i = blockIdx.x * blockDim.x + threadIdx.x;
  if (i < n) x[i] = tanhf(x[i]);
}

// ---------------------------------------------------------------------------
// fc2: y[r] = W[r,:] . h + b[r]   (block per row, 256 threads)
// ---------------------------------------------------------------------------
__global__ void fc2_k(const float* __restrict__ W, const float* __restrict__ h,
                      const float* __restrict__ b, float* __restrict__ y, int cols) {
  int r = blockIdx.x;
  const float* wp = W + (size_t)r * cols;
  float s = 0.f;
  for (int j = threadIdx.x; j < cols; j += blockDim.x) s = fmaf(wp[j], h[j], s);
  for (int o = 32; o; o >>= 1) s += __shfl_down(s, o);
  __shared__ float sh[4];
  int wv = threadIdx.x >> 6, ln = threadIdx.x & 63;
  if (ln == 0) sh[wv] = s;
  __syncthreads();
  if (threadIdx.x == 0) y[r] = sh[0] + sh[1] + sh[2] + sh[3] + b[r];
}

// ---------------------------------------------------------------------------
// Serial spiking scan, single wave.
// Round-6 evidence: VGPR=80 with 138 live weights -> RA "spilled" weights to
// AGPRs (128-unified = 4-waves/EU budget), costing a v_accvgpr_read per use
// (~830 cy/step). This round:
//  (a) amdgpu_waves_per_eu(1): unlock the full register budget.
//  (b) in-loop asm uses of every weight pair: arch-VGPR residency each iter.
//  (c) column-pair packing: W[j] = {w[j][colA], w[j][colB]} (v2f); broadcast
//      p[j] once (readlane) and splat to both halves -> one v_pk_fma_f32 per
//      j covers BOTH columns (packed f32 is full-rate on CDNA4).
// Target ~300-430 cy/step.
// ---------------------------------------------------------------------------
__device__ __forceinline__ float rlf(float v, int lane) {
  return __uint_as_float(__builtin_amdgcn_readlane(__float_as_uint(v), lane));
}

#define G1(X) X(0) X(1) X(2) X(3) X(4) X(5) X(6) X(7) X(8) X(9) X(10) X(11) \
  X(12) X(13) X(14) X(15) X(16) X(17) X(18) X(19) X(20) X(21) X(22) X(23)
#define G2(X) X(24) X(25) X(26) X(27) X(28) X(29) X(30) X(31) X(32) X(33) \
  X(34) X(35) X(36) X(37) X(38) X(39) X(40) X(41) X(42) X(43) X(44) X(45) \
  X(46) X(47)
#define G3(X) X(48) X(49) X(50) X(51) X(52) X(53) X(54) X(55) X(56) X(57) \
  X(58) X(59) X(60) X(61) X(62) X(63) X(64) X(65) X(66) X(67) X(68)
#define P69(X) G1(X) G2(X) G3(X)

__global__ __launch_bounds__(64)
__attribute__((amdgpu_waves_per_eu(1)))
void scan_k(const float* __restrict__ wmat, const float* __restrict__ start,
            float* __restrict__ out, float* __restrict__ dummy, int steps) {
  const int l = threadIdx.x;                 // 0..63
  const int colA = l;
  const int colB = (l < 5) ? 64 + l : l;     // dup for l>=5 (harmless)

  // weight pair per j: {w[j][colA], w[j][colB]}, pinned non-rematerializable
#define DECLW(j)                               \
  v2f W##j;                                    \
  W##j.x = wmat[(j) * 69 + colA];              \
  W##j.y = wmat[(j) * 69 + colB];              \
  asm volatile("" : "+v"(W##j));
  P69(DECLW)
#undef DECLW

  float px = start[colA];
  float py = start[colB];

  // store pointers: primary (cols 0..63), secondary (cols 64..68 on lanes
  // 0..4, dummy elsewhere) -> hot loop branch-free / convergent
  float* o1 = out + l;
  float* o2 = (l < 5) ? (out + 64 + l) : (dummy + l);
  const ptrdiff_t inc2 = (l < 5) ? 69 : 0;

#define USEW(j) "v"(W##j),
  // one MAC covers BOTH columns: splat p[j] into a v2f, packed fma
#define MAC(j, c) {                                        \
    float b = rlf(((j) < 64) ? px : py, (j) & 63);         \
    v2f bb; bb.x = b; bb.y = b;                            \
    acc##c = __builtin_elementwise_fma(bb, W##j, acc##c);  \
  }

  for (int step = 0; step < steps; ++step) {
    // force all weight pairs into arch VGPRs at loop top (no code if already
    // resident; split into 3 asm stmts to stay clear of operand limits)
    asm volatile("" :: G1(USEW) "i"(0));
    asm volatile("" :: G2(USEW) "i"(0));
    asm volatile("" :: G3(USEW) "i"(0));

    v2f acc0 = {0.f, 0.f}, acc1 = {0.f, 0.f};
    v2f acc2 = {0.f, 0.f}, acc3 = {0.f, 0.f};

    MAC(0, 0)  MAC(1, 1)  MAC(2, 2)  MAC(3, 3)
    MAC(4, 0)  MAC(5, 1)  MAC(6, 2)  MAC(7, 3)
    MAC(8, 0)  MAC(9, 1)  MAC(10, 2) MAC(11, 3)
    MAC(12, 0) MAC(13, 1) MAC(14, 2) MAC(15, 3)
    MAC(16, 0) MAC(17, 1) MAC(18, 2) MAC(19, 3)
    MAC(20, 0) MAC(21, 1) MAC(22, 2) MAC(23, 3)
    MAC(24, 0) MAC(25, 1) MAC(26, 2) MAC(27, 3)
    MAC(28, 0) MAC(29, 1) MAC(30, 2) MAC(31, 3)
    MAC(32, 0) MAC(33, 1) MAC(34, 2) MAC(35, 3)
    MAC(36, 0) MAC(37, 1) MAC(38, 2) MAC(39, 3)
    MAC(40, 0) MAC(41, 1) MAC(42, 2) MAC(43, 3)
    MAC(44, 0) MAC(45, 1) MAC(46, 2) MAC(47, 3)
    MAC(48, 0) MAC(49, 1) MAC(50, 2) MAC(51, 3)
    MAC(52, 0) MAC(53, 1) MAC(54, 2) MAC(55, 3)
    MAC(56, 0) MAC(57, 1) MAC(58, 2) MAC(59, 3)
    MAC(60, 0) MAC(61, 1) MAC(62, 2) MAC(63, 3)
    MAC(64, 0) MAC(65, 1) MAC(66, 2) MAC(67, 3)
    MAC(68, 0)

    float sA = (acc0.x + acc1.x) + (acc2.x + acc3.x);
    float sB = (acc0.y + acc1.y) + (acc2.y + acc3.y);

    // tanh(x) = 1 - 2/(exp(2x)+1), saturates to exactly +/-1
    float eA = __expf(2.f * sA);
    float tA = fmaf(-2.f, __builtin_amdgcn_rcpf(eA + 1.f), 1.f);
    float eB = __expf(2.f * sB);
    float tB = fmaf(-2.f, __builtin_amdgcn_rcpf(eB + 1.f), 1.f);

    float npx = tA - px;
    float npy = tB - py;

    *o1 = npx;  o1 += 69;          // fire-and-forget
    *o2 = npy;  o2 += inc2;
    px = npx;
    py = npy;
  }
#undef MAC
#undef USEW
}

// ---------------------------------------------------------------------------
extern "C" void kernel_launch(void* const* d_in, const int* in_sizes, int n_in,
                              void* d_out, int out_size, void* d_ws, size_t ws_size,
                              hipStream_t stream) {
  const float* x    = (const float*)d_in[0];
  const float* strt = (const float*)d_in[1];   // (200,69)
  const float* W_in = (const float*)d_in[2];
  const float* b_in = (const float*)d_in[3];
  const float* w1   = (const float*)d_in[4];
  const float* w2   = (const float*)d_in[5];
  const float* w3   = (const float*)d_in[6];
  const float* w4   = (const float*)d_in[7];
  const float* w5   = (const float*)d_in[8];
  const float* g1   = (const float*)d_in[9];
  const float* be1  = (const float*)d_in[10];
  const float* g2   = (const float*)d_in[11];
  const float* be2  = (const float*)d_in[12];
  const float* g3   = (const float*)d_in[13];
  const float* be3  = (const float*)d_in[14];
  const float* g4   = (const float*)d_in[15];
  const float* be4  = (const float*)d_in[16];
  const float* W_d2 = (const float*)d_in[17];
  const float* b_d2 = (const float*)d_in[18];
  float* out = (float*)d_out;

  // workspace layout (floats): fc1 16384 | A 204800 | B 409600 | stats | wmat
  float* ws   = (float*)d_ws;
  float* fc1  = ws;             // 12800 == (512,5,5); dead by scan time -> dummy
  float* A    = ws + 16384;     // max 204800 (layer3 out)
  float* B    = A + 204800;     // max 409600 (layer4 out)
  float* mean = B + 409600;     // 512
  float* rstd = mean + 512;     // 512
  float* wmat = rstd + 512;     // 4761

  fc1_k<<<12800 / 4, 256, 0, stream>>>(W_in, x, b_in, fc1, 12800, 2048);

  // layer1: (512,5,5) -up2+conv-> A (512,10,10)
  conv_k<1><<<(512 * 100 + 255) / 256, 256, 0, stream>>>(fc1, w1, A, 512, 512, 10, 10, 5, 5);
  stats_k<<<512, 256, 0, stream>>>(A, mean, rstd, 100);
  bnrelu_k<<<(51200 + 255) / 256, 256, 0, stream>>>(A, mean, rstd, g1, be1, 100, 51200);

  // layer2 -> B (256,20,20)
  conv_k<1><<<(256 * 400 + 255) / 256, 256, 0, stream>>>(A, w2, B, 512, 256, 20, 20, 10, 10);
  stats_k<<<256, 256, 0, stream>>>(B, mean, rstd, 400);
  bnrelu_k<<<(102400 + 255) / 256, 256, 0, stream>>>(B, mean, rstd, g2, be2, 400, 102400);

  // layer3 -> A (128,40,40)
  conv_k<1><<<(128 * 1600 + 255) / 256, 256, 0, stream>>>(B, w3, A, 256, 128, 40, 40, 20, 20);
  stats_k<<<128, 256, 0, stream>>>(A, mean, rstd, 1600);
  bnrelu_k<<<(204800 + 255) / 256, 256, 0, stream>>>(A, mean, rstd, g3, be3, 1600, 204800);

  // layer4 -> B (64,80,80)
  conv_k<1><<<(64 * 6400 + 255) / 256, 256, 0, stream>>>(A, w4, B, 128, 64, 80, 80, 40, 40);
  stats_k<<<64, 256, 0, stream>>>(B, mean, rstd, 6400);
  bnrelu_k<<<(409600 + 255) / 256, 256, 0, stream>>>(B, mean, rstd, g4, be4, 6400, 409600);

  // layer5: conv (no upsample) -> A (1,80,80), then tanh; A free (layer3 done)
  conv_k<0><<<(6400 + 255) / 256, 256, 0, stream>>>(B, w5, A, 64, 1, 80, 80, 80, 80);
  tanh_k<<<(6400 + 255) / 256, 256, 0, stream>>>(A, 6400);

  // fc2 -> coupling matrix w (69,69)
  fc2_k<<<4761, 256, 0, stream>>>(W_d2, A, b_d2, wmat, 6400);

  // the serial spiking recurrence: 99800 steps, single wave, packed pk-fma
  scan_k<<<1, 64, 0, stream>>>(wmat, strt + 199 * 69, out, fc1 /*dummy*/, 99800);
}